// Round 10
// baseline (220.016 us; speedup 1.0000x reference)
//
#include <hip/hip_runtime.h>

// Problem constants (match reference setup_inputs()).
#define Nn 50000
#define Rr 4
#define Dd 5
#define Ee 5000000
#define Bb 4
#define NRr (Nn * Rr)     // 200000
#define NDd (Nn * Dd)     // 250000
#define OUT_STRIDE (18 * Nn)
#define CFULL (Bb * NRr)  // one full i_rec copy: 800000 floats = 3.2 MB
#define HROWS (NRr / 2)   // 100000 rows per half (tier B)
#define CHALF (Bb * HROWS) // half copy: 400000 floats = 1.6 MB
#define NHALF (Nn / 2)     // 25000 neurons per half

typedef int   v4i __attribute__((ext_vector_type(4)));
typedef float v4f __attribute__((ext_vector_type(4)));

struct P {
    const float* inputs; const float* z_buf; const float* v; const float* r;
    const float* asc1; const float* asc2; const float* psc_rise; const float* psc;
    const float* rec_w; const int* rec_rows; const int* rec_cols;
    const float* syn_decay; const float* psc_initial; const float* t_ref;
    const float* asc_amps; const float* k; const float* v_th; const float* e_l;
    const float* v_reset; const float* g; const float* decay;
    const float* current_factor; const float* vscale; const float* voffset;
    float* out; float* copies; unsigned char* z_pack;
    int nzero4;   // float4 count to zero in K1 (tier-dependent)
};

__device__ __forceinline__ unsigned my_xcc() {
    unsigned xcc;
    asm volatile("s_getreg_b32 %0, hwreg(HW_REG_XCC_ID)" : "=s"(xcc));
    return xcc & 7u;
}

// ---------------------------------------------------------------------------
// Kernel 1: zero the accumulator copies (grid-stride), pack z_buf into
// per-column 4-bit batch masks, and do the ENTIRE i_rec-independent neuron
// update (all outputs except new_psc_rise). Output layout per batch:
//   [0,N)=new_z [N,2N)=out_v [2N,3N)=new_r [3N,4N)=asc1 [4N,5N)=asc2
//   [5N,9N)=psc_rise(reduce) [9N,13N)=psc [13N,18N)=shifted z_buf
// ---------------------------------------------------------------------------
__global__ __launch_bounds__(256) void pack_neuron_kernel(P p) {
    int i = blockIdx.x * 256 + threadIdx.x;
    int nthreads = gridDim.x * 256;

    for (int t = i; t < p.nzero4; t += nthreads)
        ((float4*)p.copies)[t] = make_float4(0.f, 0.f, 0.f, 0.f);

    if (i < NDd) {
        unsigned m = 0;
#pragma unroll
        for (int b = 0; b < Bb; ++b)
            if (p.z_buf[(size_t)b * NDd + i] != 0.0f) m |= (1u << b);
        p.z_pack[i] = (unsigned char)m;
    }

    if (i < Bb * Nn) {
        int b = i / Nn;
        int n = i - b * Nn;
        const size_t bn  = (size_t)b * Nn + n;
        const size_t bnr = (size_t)b * NRr + (size_t)n * 4;

        float prev_z = p.z_buf[(size_t)b * NDd + n];
        float4 pr = *(const float4*)(p.psc_rise + bnr);
        float4 pc = *(const float4*)(p.psc + bnr);
        float4 sd = *(const float4*)(p.syn_decay + (size_t)n * 4);

        float4 npc;
        npc.x = pc.x * sd.x + sd.x * pr.x;
        npc.y = pc.y * sd.y + sd.y * pr.y;
        npc.z = pc.z * sd.z + sd.z * pr.z;
        npc.w = pc.w * sd.w + sd.w * pr.w;
        float input_current = pc.x + pc.y + pc.z + pc.w;   // OLD psc

        float new_r = fmaxf(p.r[bn] + prev_z * p.t_ref[n] - 1.0f, 0.0f);

        float2 kv = *(const float2*)(p.k + (size_t)n * 2);
        float2 aa = *(const float2*)(p.asc_amps + (size_t)n * 2);
        float kk0 = 1.0f / (1.0f + expf(-kv.x));
        float kk1 = 1.0f / (1.0f + expf(-kv.y));
        float a1 = p.asc1[bn];
        float a2 = p.asc2[bn];
        float na1 = expf(-kk0) * a1 + prev_z * aa.x;
        float na2 = expf(-kk1) * a2 + prev_z * aa.y;

        float vth = p.v_th[n];
        float el  = p.e_l[n];
        float reset_current = prev_z * (p.v_reset[n] - vth);
        float c1 = input_current + a1 + a2 + p.g[n] * el;  // OLD asc
        float new_v = p.decay[n] * p.v[bn] + p.current_factor[n] * c1
                      + reset_current;
        float v_sc = (new_v - vth) / (vth - el);
        float new_z = (v_sc > 0.0f) ? 1.0f : 0.0f;
        if (new_r > 0.0f) new_z = 0.0f;
        float out_v = new_v * p.vscale[n] + p.voffset[n];

        float* ob = p.out + (size_t)b * OUT_STRIDE;
        ob[n]          = new_z;
        ob[Nn + n]     = out_v;
        ob[2 * Nn + n] = new_r;
        ob[3 * Nn + n] = na1;
        ob[4 * Nn + n] = na2;
        *(float4*)(ob + 9 * Nn + (size_t)n * 4) = npc;
        ob[13 * Nn + n] = new_z;
#pragma unroll
        for (int d = 0; d < Dd - 1; ++d)
            ob[14 * Nn + (size_t)d * Nn + n] =
                p.z_buf[(size_t)b * NDd + (size_t)d * Nn + n];
    }
}

// ---------------------------------------------------------------------------
// Tier A: edge scatter into the XCD-PRIVATE full copy with RELAXED
// WORKGROUP-SCOPE atomics. Atomics execute (and stay cached) in the local
// XCD's L2 instead of writing through the device coherence point — the
// R1..R9 wall's fingerprint was 1.04M x 32 B HBM write-throughs. Each copy
// is touched only by workgroups on that XCD; the end-of-dispatch release
// makes all copies visible to the reduce kernel.
// ---------------------------------------------------------------------------
__global__ __launch_bounds__(256) void edge_priv8(P p) {
    int tid = blockIdx.x * 256 + threadIdx.x;
    if (tid >= Ee / 4) return;
    float* my = p.copies + (size_t)my_xcc() * CFULL;

    v4i c = ((const v4i*)p.rec_cols)[tid];
    unsigned m0 = p.z_pack[c.x];
    unsigned m1 = p.z_pack[c.y];
    unsigned m2 = p.z_pack[c.z];
    unsigned m3 = p.z_pack[c.w];
    if (!(m0 | m1 | m2 | m3)) return;
    v4i rw = ((const v4i*)p.rec_rows)[tid];
    v4f w  = ((const v4f*)p.rec_w)[tid];
    auto acc = [&](int idx, float wv) {
        __hip_atomic_fetch_add(&my[idx], wv, __ATOMIC_RELAXED,
                               __HIP_MEMORY_SCOPE_WORKGROUP);
    };
    auto do_edge = [&](unsigned mm, int row, float wv) {
        if (mm & 1u) acc(0 * NRr + row, wv);
        if (mm & 2u) acc(1 * NRr + row, wv);
        if (mm & 4u) acc(2 * NRr + row, wv);
        if (mm & 8u) acc(3 * NRr + row, wv);
    };
    do_edge(m0, rw.x, w.x);
    do_edge(m1, rw.y, w.y);
    do_edge(m2, rw.z, w.z);
    do_edge(m3, rw.w, w.w);
}

// Tier A reduce: psc_rise = sd*pr + (sum8 + inputs)*pi.
__global__ __launch_bounds__(256) void reduce8(P p) {
    int tid = blockIdx.x * 256 + threadIdx.x;
    if (tid >= Bb * Nn) return;
    int b = tid / Nn;
    int n = tid - b * Nn;
    const size_t bnr = (size_t)b * NRr + (size_t)n * 4;
    float4 s = make_float4(0.f, 0.f, 0.f, 0.f);
#pragma unroll
    for (int cp = 0; cp < 8; ++cp) {
        float4 t = *(const float4*)(p.copies + (size_t)cp * CFULL + bnr);
        s.x += t.x; s.y += t.y; s.z += t.z; s.w += t.w;
    }
    float4 in4 = *(const float4*)(p.inputs + bnr);
    float4 pr  = *(const float4*)(p.psc_rise + bnr);
    float4 sd  = *(const float4*)(p.syn_decay + (size_t)n * 4);
    float4 pi  = *(const float4*)(p.psc_initial + (size_t)n * 4);
    float4 npr;
    npr.x = sd.x * pr.x + (s.x + in4.x) * pi.x;
    npr.y = sd.y * pr.y + (s.y + in4.y) * pi.y;
    npr.z = sd.z * pr.z + (s.z + in4.z) * pi.z;
    npr.w = sd.w * pr.w + (s.w + in4.w) * pi.w;
    float* ob = p.out + (size_t)b * OUT_STRIDE;
    *(float4*)(ob + 5 * Nn + (size_t)n * 4) = npr;
}

// ---------------------------------------------------------------------------
// Tier B: same idea with HALF-row-range copies (8 x 1.6 MB fits the proven
// 13.05 MB workspace). Two passes over the edge list; pass p handles rows in
// [p*HROWS,(p+1)*HROWS). Second pass's stream reads come from L3.
// ---------------------------------------------------------------------------
__global__ __launch_bounds__(256) void edge_priv8_half(P p, int pass) {
    int tid = blockIdx.x * 256 + threadIdx.x;
    if (tid >= Ee / 4) return;
    float* my = p.copies + (size_t)my_xcc() * CHALF;
    const int base = pass * HROWS;

    v4i rw = ((const v4i*)p.rec_rows)[tid];
    unsigned r0 = (unsigned)(rw.x - base);
    unsigned r1 = (unsigned)(rw.y - base);
    unsigned r2 = (unsigned)(rw.z - base);
    unsigned r3 = (unsigned)(rw.w - base);
    bool a0 = r0 < HROWS, a1 = r1 < HROWS, a2 = r2 < HROWS, a3 = r3 < HROWS;
    if (!(a0 | a1 | a2 | a3)) return;

    v4i c = ((const v4i*)p.rec_cols)[tid];
    unsigned m0 = a0 ? p.z_pack[c.x] : 0u;
    unsigned m1 = a1 ? p.z_pack[c.y] : 0u;
    unsigned m2 = a2 ? p.z_pack[c.z] : 0u;
    unsigned m3 = a3 ? p.z_pack[c.w] : 0u;
    if (!(m0 | m1 | m2 | m3)) return;
    v4f w = ((const v4f*)p.rec_w)[tid];
    auto acc = [&](int idx, float wv) {
        __hip_atomic_fetch_add(&my[idx], wv, __ATOMIC_RELAXED,
                               __HIP_MEMORY_SCOPE_WORKGROUP);
    };
    auto do_edge = [&](unsigned mm, unsigned rr, float wv) {
        if (mm & 1u) acc(0 * HROWS + (int)rr, wv);
        if (mm & 2u) acc(1 * HROWS + (int)rr, wv);
        if (mm & 4u) acc(2 * HROWS + (int)rr, wv);
        if (mm & 8u) acc(3 * HROWS + (int)rr, wv);
    };
    do_edge(m0, r0, w.x);
    do_edge(m1, r1, w.y);
    do_edge(m2, r2, w.z);
    do_edge(m3, r3, w.w);
}

// Tier B reduce: handles neurons of its half, then RE-ZEROS the copies so
// the next edge pass starts clean (kernel boundary orders the stores).
__global__ __launch_bounds__(256) void reduce8_half(P p, int pass) {
    int tid = blockIdx.x * 256 + threadIdx.x;
    if (tid >= Bb * NHALF) return;
    int b = tid / NHALF;
    int nh = tid - b * NHALF;              // neuron index within half
    int n = pass * NHALF + nh;             // global neuron index
    const size_t cof = (size_t)b * HROWS + (size_t)nh * 4;  // copy offset
    float4 s = make_float4(0.f, 0.f, 0.f, 0.f);
#pragma unroll
    for (int cp = 0; cp < 8; ++cp) {
        float* src = p.copies + (size_t)cp * CHALF + cof;
        float4 t = *(const float4*)src;
        s.x += t.x; s.y += t.y; s.z += t.z; s.w += t.w;
        *(float4*)src = make_float4(0.f, 0.f, 0.f, 0.f);
    }
    const size_t bnr = (size_t)b * NRr + (size_t)n * 4;
    float4 in4 = *(const float4*)(p.inputs + bnr);
    float4 pr  = *(const float4*)(p.psc_rise + bnr);
    float4 sd  = *(const float4*)(p.syn_decay + (size_t)n * 4);
    float4 pi  = *(const float4*)(p.psc_initial + (size_t)n * 4);
    float4 npr;
    npr.x = sd.x * pr.x + (s.x + in4.x) * pi.x;
    npr.y = sd.y * pr.y + (s.y + in4.y) * pi.y;
    npr.z = sd.z * pr.z + (s.z + in4.z) * pi.z;
    npr.w = sd.w * pr.w + (s.w + in4.w) * pi.w;
    float* ob = p.out + (size_t)b * OUT_STRIDE;
    *(float4*)(ob + 5 * Nn + (size_t)n * 4) = npr;
}

// ---------------------------------------------------------------------------
// Tier C fallback: proven R9 device-atomic path.
// ---------------------------------------------------------------------------
__global__ __launch_bounds__(256) void edge_dev(P p) {
    int tid = blockIdx.x * 256 + threadIdx.x;
    if (tid >= Ee / 4) return;
    v4i c = ((const v4i*)p.rec_cols)[tid];
    unsigned m0 = p.z_pack[c.x], m1 = p.z_pack[c.y];
    unsigned m2 = p.z_pack[c.z], m3 = p.z_pack[c.w];
    if (!(m0 | m1 | m2 | m3)) return;
    v4i rw = ((const v4i*)p.rec_rows)[tid];
    v4f w  = ((const v4f*)p.rec_w)[tid];
    float* i_rec = p.copies;
    auto do_edge = [&](unsigned mm, int row, float wv) {
        if (mm & 1u) atomicAdd(&i_rec[0 * NRr + row], wv);
        if (mm & 2u) atomicAdd(&i_rec[1 * NRr + row], wv);
        if (mm & 4u) atomicAdd(&i_rec[2 * NRr + row], wv);
        if (mm & 8u) atomicAdd(&i_rec[3 * NRr + row], wv);
    };
    do_edge(m0, rw.x, w.x);
    do_edge(m1, rw.y, w.y);
    do_edge(m2, rw.z, w.z);
    do_edge(m3, rw.w, w.w);
}

__global__ __launch_bounds__(256) void psc_rise_dev(P p) {
    int tid = blockIdx.x * 256 + threadIdx.x;
    if (tid >= Bb * Nn) return;
    int b = tid / Nn;
    int n = tid - b * Nn;
    const size_t bnr = (size_t)b * NRr + (size_t)n * 4;
    float4 ir  = *(const float4*)(p.copies + bnr);
    float4 in4 = *(const float4*)(p.inputs + bnr);
    float4 pr  = *(const float4*)(p.psc_rise + bnr);
    float4 sd  = *(const float4*)(p.syn_decay + (size_t)n * 4);
    float4 pi  = *(const float4*)(p.psc_initial + (size_t)n * 4);
    float4 npr;
    npr.x = sd.x * pr.x + (ir.x + in4.x) * pi.x;
    npr.y = sd.y * pr.y + (ir.y + in4.y) * pi.y;
    npr.z = sd.z * pr.z + (ir.z + in4.z) * pi.z;
    npr.w = sd.w * pr.w + (ir.w + in4.w) * pi.w;
    float* ob = p.out + (size_t)b * OUT_STRIDE;
    *(float4*)(ob + 5 * Nn + (size_t)n * 4) = npr;
}

extern "C" void kernel_launch(void* const* d_in, const int* in_sizes, int n_in,
                              void* d_out, int out_size, void* d_ws, size_t ws_size,
                              hipStream_t stream) {
    P p;
    p.inputs        = (const float*)d_in[0];
    p.z_buf         = (const float*)d_in[1];
    p.v             = (const float*)d_in[2];
    p.r             = (const float*)d_in[3];
    p.asc1          = (const float*)d_in[4];
    p.asc2          = (const float*)d_in[5];
    p.psc_rise      = (const float*)d_in[6];
    p.psc           = (const float*)d_in[7];
    p.rec_w         = (const float*)d_in[8];
    p.rec_rows      = (const int*)d_in[9];
    p.rec_cols      = (const int*)d_in[10];
    p.syn_decay     = (const float*)d_in[11];
    p.psc_initial   = (const float*)d_in[12];
    p.t_ref         = (const float*)d_in[13];
    p.asc_amps      = (const float*)d_in[14];
    p.k             = (const float*)d_in[15];
    p.v_th          = (const float*)d_in[16];
    p.v_reset       = (const float*)d_in[18];
    p.e_l           = (const float*)d_in[17];
    p.g             = (const float*)d_in[19];
    p.decay         = (const float*)d_in[20];
    p.current_factor= (const float*)d_in[21];
    p.vscale        = (const float*)d_in[22];
    p.voffset       = (const float*)d_in[23];
    p.out           = (float*)d_out;

    const size_t needA = (size_t)8 * CFULL * 4 + NDd;  // 25,850,000
    const size_t needB = (size_t)8 * CHALF * 4 + NDd;  // 13,050,000
    p.copies = (float*)d_ws;

    const int gridK1   = (NDd + 255) / 256;
    const int gridEdge = (Ee / 4 + 255) / 256;

    if (ws_size >= needA) {
        p.z_pack = (unsigned char*)d_ws + (size_t)8 * CFULL * 4;
        p.nzero4 = 8 * CFULL / 4;
        pack_neuron_kernel<<<gridK1, 256, 0, stream>>>(p);
        edge_priv8<<<gridEdge, 256, 0, stream>>>(p);
        reduce8<<<(Bb * Nn + 255) / 256, 256, 0, stream>>>(p);
    } else if (ws_size >= needB) {
        p.z_pack = (unsigned char*)d_ws + (size_t)8 * CHALF * 4;
        p.nzero4 = 8 * CHALF / 4;
        pack_neuron_kernel<<<gridK1, 256, 0, stream>>>(p);
        edge_priv8_half<<<gridEdge, 256, 0, stream>>>(p, 0);
        reduce8_half<<<(Bb * NHALF + 255) / 256, 256, 0, stream>>>(p, 0);
        edge_priv8_half<<<gridEdge, 256, 0, stream>>>(p, 1);
        reduce8_half<<<(Bb * NHALF + 255) / 256, 256, 0, stream>>>(p, 1);
    } else {
        p.z_pack = (unsigned char*)d_ws + (size_t)CFULL * 4;
        p.nzero4 = CFULL / 4;
        pack_neuron_kernel<<<gridK1, 256, 0, stream>>>(p);
        edge_dev<<<gridEdge, 256, 0, stream>>>(p);
        psc_rise_dev<<<(Bb * Nn + 255) / 256, 256, 0, stream>>>(p);
    }
}

// Round 11
// 202.349 us; speedup vs baseline: 1.0873x; 1.0873x over previous
//
#include <hip/hip_runtime.h>

// Problem constants (match reference setup_inputs()).
#define Nn 50000
#define Rr 4
#define Dd 5
#define Ee 5000000
#define Bb 4
#define NRr (Nn * Rr)   // 200000
#define NDd (Nn * Dd)   // 250000
#define ZW 7814         // ceil(250000/32)=7813 (+1 guard word for ballot hi-write)

struct P {
    const float* inputs; const float* z_buf; const float* v; const float* r;
    const float* asc1; const float* asc2; const float* psc_rise; const float* psc;
    const float* rec_w; const int* rec_rows; const int* rec_cols;
    const float* syn_decay; const float* psc_initial; const float* t_ref;
    const float* asc_amps; const float* k; const float* v_th; const float* e_l;
    const float* v_reset; const float* g; const float* decay;
    const float* current_factor; const float* vscale; const float* voffset;
    float* out; float* i_rec; unsigned char* z_pack; unsigned* zbits;
};

// ---------------------------------------------------------------------------
// Kernel 1: zero i_rec, pack z_buf into per-column 4-bit batch masks (250 KB,
// L2-resident for edge gathers) + 1-bit OR-over-batches mask (31.3 KB -> LDS).
// ---------------------------------------------------------------------------
__global__ __launch_bounds__(256) void pack_z_kernel(P p) {
    int i = blockIdx.x * 256 + threadIdx.x;
    if (i < Bb * NRr / 4)
        ((float4*)p.i_rec)[i] = make_float4(0.f, 0.f, 0.f, 0.f);
    unsigned m = 0;
    if (i < NDd) {
#pragma unroll
        for (int b = 0; b < Bb; ++b)
            if (p.z_buf[(size_t)b * NDd + i] != 0.0f) m |= (1u << b);
        p.z_pack[i] = (unsigned char)m;
    }
    unsigned long long bal = __ballot(m != 0);
    if ((i & 63) == 0 && i < NDd) {
        p.zbits[(i >> 5)]     = (unsigned)bal;
        p.zbits[(i >> 5) + 1] = (unsigned)(bal >> 32);
    }
}

// ---------------------------------------------------------------------------
// Kernel 2: edge scatter (LDS bitmask gate -> z_pack byte -> fire-and-forget
// device atomics) FUSED with all i_rec-INDEPENDENT neuron work. The edge
// path idles VALU+HBM while pinned at the memory-side atomic wall
// (~1.0M scattered RMWs at ~1/cy/XCD — WRITE_SIZE fingerprint 1.0M x 32 B
// across R1..R10), so the streaming neuron work rides underneath for free
// (verified R5: 61.5 -> 65.5 us while absorbing the whole ~10 us neuron
// kernel). Output layout per batch (18*N floats):
//   [0,N)=new_z [N,2N)=out_v [2N,3N)=new_r [3N,4N)=asc1 [4N,5N)=asc2
//   [5N,9N)=psc_rise(kernel 3) [9N,13N)=psc [13N,18N)=shifted z_buf
// ---------------------------------------------------------------------------
__global__ __launch_bounds__(256) void edge_neuron_kernel(P p) {
    __shared__ unsigned zb[ZW];
    for (int t = threadIdx.x; t < ZW; t += 256) zb[t] = p.zbits[t];
    __syncthreads();
    const int tid = blockIdx.x * 256 + threadIdx.x;

    // ---- i_rec-independent neuron update (first 200k threads) ----
    if (tid < Bb * Nn) {
        int b = tid / Nn;
        int n = tid - b * Nn;
        const size_t bn  = (size_t)b * Nn + n;
        const size_t bnr = (size_t)b * NRr + (size_t)n * 4;

        float prev_z = p.z_buf[(size_t)b * NDd + n];
        float4 pr = *(const float4*)(p.psc_rise + bnr);
        float4 pc = *(const float4*)(p.psc + bnr);
        float4 sd = *(const float4*)(p.syn_decay + (size_t)n * 4);

        float4 npc;
        npc.x = pc.x * sd.x + sd.x * pr.x;
        npc.y = pc.y * sd.y + sd.y * pr.y;
        npc.z = pc.z * sd.z + sd.z * pr.z;
        npc.w = pc.w * sd.w + sd.w * pr.w;
        float input_current = pc.x + pc.y + pc.z + pc.w;   // OLD psc

        float new_r = fmaxf(p.r[bn] + prev_z * p.t_ref[n] - 1.0f, 0.0f);

        float2 kv = *(const float2*)(p.k + (size_t)n * 2);
        float2 aa = *(const float2*)(p.asc_amps + (size_t)n * 2);
        float kk0 = 1.0f / (1.0f + expf(-kv.x));
        float kk1 = 1.0f / (1.0f + expf(-kv.y));
        float a1 = p.asc1[bn];
        float a2 = p.asc2[bn];
        float na1 = expf(-kk0) * a1 + prev_z * aa.x;
        float na2 = expf(-kk1) * a2 + prev_z * aa.y;

        float vth = p.v_th[n];
        float el  = p.e_l[n];
        float reset_current = prev_z * (p.v_reset[n] - vth);
        float c1 = input_current + a1 + a2 + p.g[n] * el;  // OLD asc
        float new_v = p.decay[n] * p.v[bn] + p.current_factor[n] * c1
                      + reset_current;
        float v_sc = (new_v - vth) / (vth - el);
        float new_z = (v_sc > 0.0f) ? 1.0f : 0.0f;
        if (new_r > 0.0f) new_z = 0.0f;
        float out_v = new_v * p.vscale[n] + p.voffset[n];

        float* ob = p.out + (size_t)b * 18 * Nn;
        ob[n]          = new_z;
        ob[Nn + n]     = out_v;
        ob[2 * Nn + n] = new_r;
        ob[3 * Nn + n] = na1;
        ob[4 * Nn + n] = na2;
        *(float4*)(ob + 9 * Nn + (size_t)n * 4) = npc;
        ob[13 * Nn + n] = new_z;
#pragma unroll
        for (int d = 0; d < Dd - 1; ++d)
            ob[14 * Nn + (size_t)d * Nn + n] =
                p.z_buf[(size_t)b * NDd + (size_t)d * Nn + n];
    }

    // ---- edge scatter (one quad per thread) ----
    if (tid < Ee / 4) {
        int4 c = ((const int4*)p.rec_cols)[tid];
        unsigned h0 = (zb[(unsigned)c.x >> 5] >> (c.x & 31)) & 1u;
        unsigned h1 = (zb[(unsigned)c.y >> 5] >> (c.y & 31)) & 1u;
        unsigned h2 = (zb[(unsigned)c.z >> 5] >> (c.z & 31)) & 1u;
        unsigned h3 = (zb[(unsigned)c.w >> 5] >> (c.w & 31)) & 1u;
        if (h0 | h1 | h2 | h3) {
            int4 rw = ((const int4*)p.rec_rows)[tid];
            float4 w = ((const float4*)p.rec_w)[tid];
            float* i_rec = p.i_rec;
            auto do_edge = [&](unsigned hh, int col, int row, float wv) {
                if (hh) {
                    unsigned mm = p.z_pack[col];
                    if (mm & 1u) atomicAdd(&i_rec[0 * NRr + row], wv);
                    if (mm & 2u) atomicAdd(&i_rec[1 * NRr + row], wv);
                    if (mm & 4u) atomicAdd(&i_rec[2 * NRr + row], wv);
                    if (mm & 8u) atomicAdd(&i_rec[3 * NRr + row], wv);
                }
            };
            do_edge(h0, c.x, rw.x, w.x);
            do_edge(h1, c.y, rw.y, w.y);
            do_edge(h2, c.z, rw.z, w.z);
            do_edge(h3, c.w, rw.w, w.w);
        }
    }
}

// ---------------------------------------------------------------------------
// Kernel 3: the only i_rec consumer. npr = sd*pr + (i_rec+inputs)*pi.
// ---------------------------------------------------------------------------
__global__ __launch_bounds__(256) void psc_rise_kernel(P p) {
    int tid = blockIdx.x * 256 + threadIdx.x;
    if (tid >= Bb * Nn) return;
    int b = tid / Nn;
    int n = tid - b * Nn;
    const size_t bnr = (size_t)b * NRr + (size_t)n * 4;
    float4 ir  = *(const float4*)(p.i_rec + bnr);
    float4 in4 = *(const float4*)(p.inputs + bnr);
    float4 pr  = *(const float4*)(p.psc_rise + bnr);
    float4 sd  = *(const float4*)(p.syn_decay + (size_t)n * 4);
    float4 pi  = *(const float4*)(p.psc_initial + (size_t)n * 4);
    float4 npr;
    npr.x = sd.x * pr.x + (ir.x + in4.x) * pi.x;
    npr.y = sd.y * pr.y + (ir.y + in4.y) * pi.y;
    npr.z = sd.z * pr.z + (ir.z + in4.z) * pi.z;
    npr.w = sd.w * pr.w + (ir.w + in4.w) * pi.w;
    float* ob = p.out + (size_t)b * 18 * Nn;
    *(float4*)(ob + 5 * Nn + (size_t)n * 4) = npr;
}

extern "C" void kernel_launch(void* const* d_in, const int* in_sizes, int n_in,
                              void* d_out, int out_size, void* d_ws, size_t ws_size,
                              hipStream_t stream) {
    P p;
    p.inputs        = (const float*)d_in[0];
    p.z_buf         = (const float*)d_in[1];
    p.v             = (const float*)d_in[2];
    p.r             = (const float*)d_in[3];
    p.asc1          = (const float*)d_in[4];
    p.asc2          = (const float*)d_in[5];
    p.psc_rise      = (const float*)d_in[6];
    p.psc           = (const float*)d_in[7];
    p.rec_w         = (const float*)d_in[8];
    p.rec_rows      = (const int*)d_in[9];
    p.rec_cols      = (const int*)d_in[10];
    p.syn_decay     = (const float*)d_in[11];
    p.psc_initial   = (const float*)d_in[12];
    p.t_ref         = (const float*)d_in[13];
    p.asc_amps      = (const float*)d_in[14];
    p.k             = (const float*)d_in[15];
    p.v_th          = (const float*)d_in[16];
    p.e_l           = (const float*)d_in[17];
    p.v_reset       = (const float*)d_in[18];
    p.g             = (const float*)d_in[19];
    p.decay         = (const float*)d_in[20];
    p.current_factor= (const float*)d_in[21];
    p.vscale        = (const float*)d_in[22];
    p.voffset       = (const float*)d_in[23];
    p.out           = (float*)d_out;
    // Workspace: i_rec f32[800k] @0 | z_pack u8[250k] @3,200,000 |
    //            zbits u32[ZW] @3,450,240
    p.i_rec  = (float*)d_ws;
    p.z_pack = (unsigned char*)d_ws + 3200000;
    p.zbits  = (unsigned*)((char*)d_ws + 3450240);

    pack_z_kernel<<<(NDd + 255) / 256, 256, 0, stream>>>(p);
    edge_neuron_kernel<<<(Ee / 4 + 255) / 256, 256, 0, stream>>>(p);
    psc_rise_kernel<<<(Bb * Nn + 255) / 256, 256, 0, stream>>>(p);
}